// Round 2
// baseline (112.579 us; speedup 1.0000x reference)
//
#include <hip/hip_runtime.h>
#include <stdint.h>
#include <stddef.h>

// BalancedFocalLoss fused kernel — MI355X (gfx950), round 2
//
// Math reduction:
//   z = concat(zx, zy); zn = z/||z||;  sim = zn·znT / 0.5
//   ce_i  = log( sum_{j != i} exp(sim_ij) ) - sim_{i,(i+B)%N}
//   out   = mean( ALPHA * (1-exp(-ce))^2 * ce )
// s2n = sqrt(2)*zn in bf16 so s2n_i·s2n_j == sim_ij.  sim in [-2,2] => no
// online max needed.  sim is EXACTLY symmetric under MFMA (same products,
// same HW reduction tree), so we compute only upper-triangle 128^2 tiles
// (2080 of 4096) and harvest both row-sums and col-sums per tile.
// Partial slots: tile (p,q): row-sums -> slot q*2+wc, col-sums -> slot p*2+wr.
// For a row in panel a: slots {2q,2q+1 : q>=a} from row-sums, {2p,2p+1 : p<a}
// from col-sums = all 128 slots exactly once. Deterministic, no atomics.
// pos[b] = sim[b][b+4096] harvested from tile-diagonals of q==p+32 tiles.

typedef __attribute__((ext_vector_type(8))) short short8;
typedef __attribute__((ext_vector_type(4))) float f32x4;

#define NROWS 8192
#define DDIM 256
#define NTILES 2080   // 64*65/2 panels of 128

__device__ __forceinline__ unsigned short f2bf(float f) {
  unsigned int u = __float_as_uint(f);
  u = (u + 0x7FFFu + ((u >> 16) & 1u)) >> 16;   // RNE, inputs finite
  return (unsigned short)u;
}

// ---------------- 1. row normalize + sqrt(2) scale + bf16 cast ----------------
// 256 threads = 4 waves, one row per wave. 2048 blocks.
__global__ __launch_bounds__(256) void norm_kernel(const float* __restrict__ zx,
                                                   const float* __restrict__ zy,
                                                   unsigned short* __restrict__ zn) {
  const int row = blockIdx.x * 4 + (threadIdx.x >> 6);   // 8192 rows
  const int lane = threadIdx.x & 63;                     // 4 floats each
  const float* src = (row < 4096) ? (zx + (size_t)row * DDIM)
                                  : (zy + (size_t)(row - 4096) * DDIM);
  float4 v = reinterpret_cast<const float4*>(src)[lane];
  float ss = v.x * v.x + v.y * v.y + v.z * v.z + v.w * v.w;
#pragma unroll
  for (int m = 1; m < 64; m <<= 1) ss += __shfl_xor(ss, m);
  const float sc = 1.41421356237f * rsqrtf(ss);   // sqrt(2)/||z||
  ushort4 o;
  o.x = f2bf(v.x * sc); o.y = f2bf(v.y * sc);
  o.z = f2bf(v.z * sc); o.w = f2bf(v.w * sc);
  reinterpret_cast<ushort4*>(zn + (size_t)row * DDIM)[lane] = o;
}

// ---------------- 2. upper-triangle sim GEMM + exp row/col sums ----------------
// 2080 blocks, one 128x128 tile each. 4 waves (2x2), wave tile 64x64
// (4x4 frags of 16x16x32 bf16 MFMA), BK=64, K=256 (4 steps),
// double-buffered LDS (64 KiB) via global_load_lds width-16.
__global__ __launch_bounds__(256, 2) void simtri_kernel(const unsigned short* __restrict__ zn,
                                                        float* __restrict__ partial,
                                                        float* __restrict__ pos) {
  __shared__ unsigned short smem[2][2][128 * 64];
  const int bid = blockIdx.x;
  // unrank triangular pair (p <= q), offset(p) = p*(129-p)/2
  int p = (int)((129.0f - sqrtf((float)(16641 - 8 * bid))) * 0.5f);
  p = max(0, min(63, p));
  while ((((p + 1) * (129 - (p + 1))) >> 1) <= bid) ++p;
  while (((p * (129 - p)) >> 1) > bid) --p;
  const int q = p + (bid - ((p * (129 - p)) >> 1));
  const int R0 = p << 7;
  const int C0 = q << 7;
  const bool isdiag = (p == q);
  const bool ispos = (q == p + 32);

  const int tid = threadIdx.x;
  const int lane = tid & 63;
  const int wid = tid >> 6;
  const int wr = wid >> 1;              // wave row (0/1)
  const int wc = wid & 1;               // wave col (0/1)

  const f32x4 z4 = {0.f, 0.f, 0.f, 0.f};
  f32x4 acc[4][4];
#pragma unroll
  for (int m = 0; m < 4; ++m)
#pragma unroll
    for (int n = 0; n < 4; ++n) acc[m][n] = z4;

  auto stage = [&](int buf, int which, int row0, int k0) {
    // 128 rows x 64 k, row-major; 16 KiB = 1024 x 16B units, 256 thr x 4.
    unsigned short* lb = &smem[buf][which][0];
#pragma unroll
    for (int j = 0; j < 4; ++j) {
      const int u = j * 256 + wid * 64 + lane;
      const unsigned short* g = zn + (size_t)(row0 + (u >> 3)) * DDIM + k0 + (u & 7) * 8;
      unsigned short* l = lb + (size_t)(j * 256 + wid * 64) * 8;   // wave-uniform; HW adds lane*16B
      __builtin_amdgcn_global_load_lds(
          (const __attribute__((address_space(1))) void*)g,
          (__attribute__((address_space(3))) void*)l, 16, 0, 0);
    }
  };

  stage(0, 0, R0, 0);
  if (!isdiag) stage(0, 1, C0, 0);
  __syncthreads();

  int buf = 0;
#pragma unroll
  for (int s = 0; s < 4; ++s) {
    if (s < 3) {
      stage(buf ^ 1, 0, R0, (s + 1) * 64);
      if (!isdiag) stage(buf ^ 1, 1, C0, (s + 1) * 64);
    }
    const unsigned short* A = &smem[buf][0][0];
    const unsigned short* Bm = isdiag ? A : &smem[buf][1][0];
#pragma unroll
    for (int ks = 0; ks < 2; ++ks) {
      short8 af[4], bfr[4];
#pragma unroll
      for (int m = 0; m < 4; ++m)
        af[m] = *reinterpret_cast<const short8*>(
            A + ((wr * 64 + m * 16 + (lane & 15)) * 64 + ks * 32 + (lane >> 4) * 8));
#pragma unroll
      for (int n = 0; n < 4; ++n)
        bfr[n] = *reinterpret_cast<const short8*>(
            Bm + ((wc * 64 + n * 16 + (lane & 15)) * 64 + ks * 32 + (lane >> 4) * 8));
#pragma unroll
      for (int m = 0; m < 4; ++m)
#pragma unroll
        for (int n = 0; n < 4; ++n)
          acc[m][n] = __builtin_amdgcn_mfma_f32_16x16x32_bf16(af[m], bfr[n], acc[m][n], 0, 0, 0);
    }
    buf ^= 1;
    __syncthreads();
  }

  // ---- epilogue: exp, diagonal-exclude, pos harvest, row+col accumulate ----
  float rsum[4][4];       // [m][r]  row partial over this wave's 64 cols
  float csum[4];          // [n]     col partial over this wave's 64 rows
#pragma unroll
  for (int m = 0; m < 4; ++m)
#pragma unroll
    for (int r = 0; r < 4; ++r) rsum[m][r] = 0.f;
#pragma unroll
  for (int n = 0; n < 4; ++n) csum[n] = 0.f;

#pragma unroll
  for (int m = 0; m < 4; ++m) {
    const int grow_b = R0 + wr * 64 + m * 16 + ((lane >> 4) << 2);
#pragma unroll
    for (int n = 0; n < 4; ++n) {
      const int gcol = C0 + wc * 64 + n * 16 + (lane & 15);
#pragma unroll
      for (int r = 0; r < 4; ++r) {
        const int grow = grow_b + r;
        const float val = acc[m][n][r];
        if (ispos && (gcol == grow + 4096)) pos[grow] = val;   // sim[i][i+B]
        const float e = (isdiag && (grow == gcol)) ? 0.f : __expf(val);
        rsum[m][r] += e;
        csum[n] += e;
      }
    }
  }

  // row-sums: reduce across the 16 col-lanes of each group -> slot q*2+wc
#pragma unroll
  for (int m = 0; m < 4; ++m)
#pragma unroll
    for (int r = 0; r < 4; ++r) {
      float s = rsum[m][r];
      s += __shfl_xor(s, 1); s += __shfl_xor(s, 2);
      s += __shfl_xor(s, 4); s += __shfl_xor(s, 8);
      if ((lane & 15) == 0) {
        const int grow = R0 + wr * 64 + m * 16 + ((lane >> 4) << 2) + r;
        partial[(size_t)(q * 2 + wc) * NROWS + grow] = s;
      }
    }

  // col-sums: reduce across the 4 row-groups -> slot p*2+wr (skip diagonal tile)
  if (!isdiag) {
#pragma unroll
    for (int n = 0; n < 4; ++n) {
      float c = csum[n];
      c += __shfl_xor(c, 16); c += __shfl_xor(c, 32);
      if (lane < 16)
        partial[(size_t)(p * 2 + wr) * NROWS + (C0 + wc * 64 + n * 16 + lane)] = c;
    }
  }
}

// ---------------- 3. per-row loss + reduction ----------------
__global__ __launch_bounds__(256) void d1_kernel(const float* __restrict__ partial,
                                                 const float* __restrict__ pos,
                                                 float* __restrict__ bsum) {
  const int row = blockIdx.x * 256 + threadIdx.x;   // 32 blocks x 256
  float s = 0.f;
#pragma unroll 16
  for (int c = 0; c < 128; ++c) s += partial[(size_t)c * NROWS + row];
  const float ce = __logf(s) - pos[row & 4095];
  const float pt = __expf(-ce);
  float f = (1.f - pt) * (1.f - pt) * ce;
#pragma unroll
  for (int m = 1; m < 64; m <<= 1) f += __shfl_xor(f, m);
  __shared__ float wsum[4];
  if ((threadIdx.x & 63) == 0) wsum[threadIdx.x >> 6] = f;
  __syncthreads();
  if (threadIdx.x == 0) bsum[blockIdx.x] = wsum[0] + wsum[1] + wsum[2] + wsum[3];
}

__global__ __launch_bounds__(64) void d2_kernel(const float* __restrict__ bsum,
                                                float* __restrict__ out) {
  const int l = threadIdx.x;
  float v = (l < 32) ? bsum[l] : 0.f;
#pragma unroll
  for (int m = 1; m < 64; m <<= 1) v += __shfl_xor(v, m);
  if (l == 0) out[0] = 0.25f * v / 8192.f;   // ALPHA * mean
}

extern "C" void kernel_launch(void* const* d_in, const int* in_sizes, int n_in,
                              void* d_out, int out_size, void* d_ws, size_t ws_size,
                              hipStream_t stream) {
  const float* zx = (const float*)d_in[0];
  const float* zy = (const float*)d_in[1];
  float* out = (float*)d_out;

  // workspace (~8.2 MiB): zn bf16 | pos | partial | bsum
  unsigned short* zn = (unsigned short*)d_ws;                      // 8192*256*2 = 4 MiB
  float* pos = (float*)((char*)d_ws + (size_t)NROWS * DDIM * 2);   // 16 KiB
  float* partial = pos + 4096;                                     // 128*8192*4 = 4 MiB
  float* bsum = partial + (size_t)128 * NROWS;                     // 128 B

  norm_kernel<<<2048, 256, 0, stream>>>(zx, zy, zn);
  simtri_kernel<<<NTILES, 256, 0, stream>>>(zn, partial, pos);
  d1_kernel<<<32, 256, 0, stream>>>(partial, pos, bsum);
  d2_kernel<<<1, 64, 0, stream>>>(bsum, out);
}

// Round 3
// 110.170 us; speedup vs baseline: 1.0219x; 1.0219x over previous
//
#include <hip/hip_runtime.h>
#include <stdint.h>
#include <stddef.h>

// BalancedFocalLoss fused kernel — MI355X (gfx950), round 3
//
//   z = concat(zx, zy); zn = z/||z||;  sim = zn·znT / 0.5
//   ce_i  = log( sum_{j != i} exp(sim_ij) ) - sim_{i,(i+B)%N}
//   out   = mean( ALPHA * (1-exp(-ce))^2 * ce )
//
// We store s2n = sqrt(2*log2e)*zn in bf16, so acc = s2n_i·s2n_j = log2e*sim_ij
// and exp(sim) == exp2(acc) (one v_exp_f32, no scaling mul).  In log2-domain:
//   L = log2(S) - acc_pos;  ce = ln2*L;  pt = 2^-L.
// sim symmetric => only upper-triangle 128^2 tiles (2080 of 4096); each tile
// yields row-sums (slot q*2+wc) AND col-sums (slot p*2+wr) — 128 slots/row,
// each written exactly once.  Deterministic, no atomics in the partial path.
//
// R3 structural fix: 512 blocks (2/CU, one dispatch round), block b owns tiles
// {b, b+512, ...} (4-5 each), ONE continuous double-buffered pipeline across
// all 16-20 K-steps; per-tile epilogue runs before the tile-boundary barrier
// so its exp/VALU work hides the next tile's staged-load latency.

typedef __attribute__((ext_vector_type(8))) short short8;
typedef __attribute__((ext_vector_type(4))) float f32x4;

#define NROWS 8192
#define DDIM 256
#define NTILES 2080   // 64*65/2 panels of 128
#define NBLK 512

__device__ __forceinline__ unsigned short f2bf(float f) {
  unsigned int u = __float_as_uint(f);
  u = (u + 0x7FFFu + ((u >> 16) & 1u)) >> 16;   // RNE, inputs finite
  return (unsigned short)u;
}

__device__ __forceinline__ void unrank_tile(int t, int& p_out, int& q_out) {
  // triangular pair (p <= q), offset(p) = p*(129-p)/2
  int p = (int)((129.0f - sqrtf((float)(16641 - 8 * t))) * 0.5f);
  p = max(0, min(63, p));
  while ((((p + 1) * (129 - (p + 1))) >> 1) <= t) ++p;
  while (((p * (129 - p)) >> 1) > t) --p;
  p_out = p;
  q_out = p + (t - ((p * (129 - p)) >> 1));
}

// ---------------- 1. normalize + sqrt(2*log2e) scale + bf16; zero d1 counter ----------------
__global__ __launch_bounds__(256) void norm_kernel(const float* __restrict__ zx,
                                                   const float* __restrict__ zy,
                                                   unsigned short* __restrict__ zn,
                                                   unsigned int* __restrict__ counter) {
  if (blockIdx.x == 0 && threadIdx.x == 0) *counter = 0u;
  const int row = blockIdx.x * 4 + (threadIdx.x >> 6);   // 8192 rows, 1 per wave
  const int lane = threadIdx.x & 63;
  const float* src = (row < 4096) ? (zx + (size_t)row * DDIM)
                                  : (zy + (size_t)(row - 4096) * DDIM);
  float4 v = reinterpret_cast<const float4*>(src)[lane];
  float ss = v.x * v.x + v.y * v.y + v.z * v.z + v.w * v.w;
#pragma unroll
  for (int m = 1; m < 64; m <<= 1) ss += __shfl_xor(ss, m);
  const float sc = 1.69864360f * rsqrtf(ss);   // sqrt(2*log2e)/||z||
  ushort4 o;
  o.x = f2bf(v.x * sc); o.y = f2bf(v.y * sc);
  o.z = f2bf(v.z * sc); o.w = f2bf(v.w * sc);
  reinterpret_cast<ushort4*>(zn + (size_t)row * DDIM)[lane] = o;
}

// ---------------- 2. upper-triangle sim GEMM + exp2 row/col sums ----------------
__global__ __launch_bounds__(256, 2) void simtri_kernel(const unsigned short* __restrict__ zn,
                                                        float* __restrict__ partial,
                                                        float* __restrict__ pos) {
  __shared__ unsigned short smem[2][2][128 * 64];
  const int bid = blockIdx.x;                       // 512
  const int nt = (bid < NTILES - NBLK * 4) ? 5 : 4; // 2080 = 512*4 + 32
  const int tid = threadIdx.x;
  const int lane = tid & 63;
  const int wid = tid >> 6;
  const int wr = wid >> 1;              // wave row (0/1)
  const int wc = wid & 1;               // wave col (0/1)

  const f32x4 z4 = {0.f, 0.f, 0.f, 0.f};
  f32x4 acc[4][4];
#pragma unroll
  for (int m = 0; m < 4; ++m)
#pragma unroll
    for (int n = 0; n < 4; ++n) acc[m][n] = z4;

  auto stage_one = [&](int buf, int which, int row0, int k0) {
    // 128 rows x 64 k, row-major; 16 KiB = 1024 x 16B units, 256 thr x 4.
    unsigned short* lb = &smem[buf][which][0];
#pragma unroll
    for (int j = 0; j < 4; ++j) {
      const int u = j * 256 + wid * 64 + lane;
      const unsigned short* g = zn + (size_t)(row0 + (u >> 3)) * DDIM + k0 + (u & 7) * 8;
      unsigned short* l = lb + (size_t)(j * 256 + wid * 64) * 8;   // wave-uniform; HW adds lane*16B
      __builtin_amdgcn_global_load_lds(
          (const __attribute__((address_space(1))) void*)g,
          (__attribute__((address_space(3))) void*)l, 16, 0, 0);
    }
  };
  auto stageT = [&](int buf, int p, int q, int k0) {
    stage_one(buf, 0, p << 7, k0);
    if (p != q) stage_one(buf, 1, q << 7, k0);
  };

  int cp, cq;
  unrank_tile(bid, cp, cq);
  stageT(0, cp, cq, 0);
  __syncthreads();

  int buf = 0;
  for (int i = 0; i < nt; ++i) {
    int np = cp, nq = cq;
    const bool have_next = (i + 1 < nt);
    if (have_next) unrank_tile(bid + NBLK * (i + 1), np, nq);
    const bool isdiag = (cp == cq);
    const bool ispos = (cq == cp + 32);
    const int R0 = cp << 7;
    const int C0 = cq << 7;

#pragma unroll
    for (int kk = 0; kk < 4; ++kk) {
      if (kk < 3) stageT(buf ^ 1, cp, cq, (kk + 1) * 64);
      else if (have_next) stageT(buf ^ 1, np, nq, 0);
      const unsigned short* A = &smem[buf][0][0];
      const unsigned short* Bm = isdiag ? A : &smem[buf][1][0];
#pragma unroll
      for (int ks = 0; ks < 2; ++ks) {
        short8 af[4], bfr[4];
#pragma unroll
        for (int m = 0; m < 4; ++m)
          af[m] = *reinterpret_cast<const short8*>(
              A + ((wr * 64 + m * 16 + (lane & 15)) * 64 + ks * 32 + (lane >> 4) * 8));
#pragma unroll
        for (int n = 0; n < 4; ++n)
          bfr[n] = *reinterpret_cast<const short8*>(
              Bm + ((wc * 64 + n * 16 + (lane & 15)) * 64 + ks * 32 + (lane >> 4) * 8));
#pragma unroll
        for (int m = 0; m < 4; ++m)
#pragma unroll
          for (int n = 0; n < 4; ++n)
            acc[m][n] = __builtin_amdgcn_mfma_f32_16x16x32_bf16(af[m], bfr[n], acc[m][n], 0, 0, 0);
      }
      buf ^= 1;
      if (kk < 3) __syncthreads();
    }

    // ---- epilogue (before tile-boundary barrier: overlaps staged-load latency) ----
    float rsum[4][4];       // [m][r]  row partial over this wave's 64 cols
    float csum[4];          // [n]     col partial over this wave's 64 rows
#pragma unroll
    for (int m = 0; m < 4; ++m)
#pragma unroll
      for (int r = 0; r < 4; ++r) rsum[m][r] = 0.f;
#pragma unroll
    for (int n = 0; n < 4; ++n) csum[n] = 0.f;

#pragma unroll
    for (int m = 0; m < 4; ++m)
#pragma unroll
      for (int n = 0; n < 4; ++n)
#pragma unroll
        for (int r = 0; r < 4; ++r) {
          const float e = __builtin_amdgcn_exp2f(acc[m][n][r]);
          rsum[m][r] += e;
          csum[n] += e;
        }

    // fixups: diag-exclude / pos harvest (tile-local diagonal, wr==wc waves only)
    if ((isdiag || ispos) && (wr == wc)) {
      const int hi = lane >> 4, lo = lane & 15;
#pragma unroll
      for (int m = 0; m < 4; ++m)
#pragma unroll
        for (int r = 0; r < 4; ++r)
          if (lo == 4 * hi + r) {
            if (isdiag) rsum[m][r] -= __builtin_amdgcn_exp2f(acc[m][m][r]);
            else        pos[R0 + wr * 64 + m * 16 + lo] = acc[m][m][r];  // log2-domain
          }
    }

    // row-sums: reduce across 16 col-lanes -> slot q*2+wc
#pragma unroll
    for (int m = 0; m < 4; ++m)
#pragma unroll
      for (int r = 0; r < 4; ++r) {
        float s = rsum[m][r];
        s += __shfl_xor(s, 1); s += __shfl_xor(s, 2);
        s += __shfl_xor(s, 4); s += __shfl_xor(s, 8);
        if ((lane & 15) == 0) {
          const int grow = R0 + wr * 64 + m * 16 + ((lane >> 4) << 2) + r;
          partial[(size_t)(cq * 2 + wc) * NROWS + grow] = s;
        }
      }

    // col-sums: reduce across 4 row-groups -> slot p*2+wr (skip diagonal tile)
    if (!isdiag) {
#pragma unroll
      for (int n = 0; n < 4; ++n) {
        float c = csum[n];
        c += __shfl_xor(c, 16); c += __shfl_xor(c, 32);
        if (lane < 16)
          partial[(size_t)(cp * 2 + wr) * NROWS + (C0 + wc * 64 + n * 16 + lane)] = c;
      }
    }

    // reset acc for next tile
#pragma unroll
    for (int m = 0; m < 4; ++m)
#pragma unroll
      for (int n = 0; n < 4; ++n) acc[m][n] = z4;

    __syncthreads();   // next-tile staged data ready; smem[buf^1] safe to overwrite
    cp = np; cq = nq;
  }
}

// ---------------- 3. per-row loss + full reduction (last-block-done finish) ----------------
__global__ __launch_bounds__(256) void d1_kernel(const float* __restrict__ partial,
                                                 const float* __restrict__ pos,
                                                 float* __restrict__ bsum,
                                                 float* __restrict__ out,
                                                 unsigned int* __restrict__ counter) {
  const int row = blockIdx.x * 256 + threadIdx.x;   // 32 blocks x 256
  float s = 0.f;
#pragma unroll 16
  for (int c = 0; c < 128; ++c) s += partial[(size_t)c * NROWS + row];
  const float L = __log2f(s) - pos[row & 4095];     // log2-domain ce
  const float pt = __builtin_amdgcn_exp2f(-L);
  const float ce = 0.69314718056f * L;
  float f = (1.f - pt) * (1.f - pt) * ce;
#pragma unroll
  for (int m = 1; m < 64; m <<= 1) f += __shfl_xor(f, m);
  __shared__ float wsum[4];
  if ((threadIdx.x & 63) == 0) wsum[threadIdx.x >> 6] = f;
  __syncthreads();
  if (threadIdx.x == 0) {
    bsum[blockIdx.x] = wsum[0] + wsum[1] + wsum[2] + wsum[3];
    __threadfence();
    if (atomicAdd(counter, 1u) == 31u) {        // last block: deterministic finish
      __threadfence();
      float v = 0.f;
#pragma unroll
      for (int c = 0; c < 32; ++c) v += ((const volatile float*)bsum)[c];
      out[0] = 0.25f * v / 8192.f;              // ALPHA * mean
    }
  }
}

extern "C" void kernel_launch(void* const* d_in, const int* in_sizes, int n_in,
                              void* d_out, int out_size, void* d_ws, size_t ws_size,
                              hipStream_t stream) {
  const float* zx = (const float*)d_in[0];
  const float* zy = (const float*)d_in[1];
  float* out = (float*)d_out;

  // workspace (~8.02 MiB): zn bf16 | pos | partial | bsum | counter
  unsigned short* zn = (unsigned short*)d_ws;                      // 8192*256*2 = 4 MiB
  float* pos = (float*)((char*)d_ws + (size_t)NROWS * DDIM * 2);   // 16 KiB
  float* partial = pos + 4096;                                     // 128*8192*4 = 4 MiB
  float* bsum = partial + (size_t)128 * NROWS;                     // 128 B
  unsigned int* counter = (unsigned int*)(bsum + 32);              // 4 B

  norm_kernel<<<2048, 256, 0, stream>>>(zx, zy, zn, counter);
  simtri_kernel<<<NBLK, 256, 0, stream>>>(zn, partial, pos);
  d1_kernel<<<32, 256, 0, stream>>>(partial, pos, bsum, out, counter);
}

// Round 5
// 104.868 us; speedup vs baseline: 1.0735x; 1.0506x over previous
//
#include <hip/hip_runtime.h>
#include <stdint.h>
#include <stddef.h>

// BalancedFocalLoss fused kernel — MI355X (gfx950), round 4 (resubmit; R4 bench
// failed on GPU acquisition, kernel unmeasured)
//
//   z = concat(zx, zy); zn = z/||z||;  sim = zn·znT / 0.5
//   ce_i  = log( sum_{j != i} exp(sim_ij) ) - sim_{i,(i+B)%N}
//   out   = mean( ALPHA * (1-exp(-ce))^2 * ce )
//
// s2n = sqrt(2*log2e)*zn bf16 => acc = log2e*sim; exp(sim) == exp2(acc).
// Upper-triangle 128^2 tiles only (2080); each tile emits row-sums (slot
// q*2+wc) and col-sums (slot p*2+wr) — 128 slots/row, each written once.
//
// R4: (1) contiguous row-major tile runs per block + XCD-chunk swizzle
//     (A-panel L1/L2-hot across the whole run — R3's strided order was the
//     latency regression); (2) T2 LDS XOR-swizzle done both-sides (linear
//     LDS dest for global_load_lds, pre-swizzled GLOBAL source, XOR'd
//     ds_read) killing the 16-phase bank serialization on frag reads.

typedef __attribute__((ext_vector_type(8))) short short8;
typedef __attribute__((ext_vector_type(4))) float f32x4;

#define NROWS 8192
#define DDIM 256
#define NTILES 2080   // 64*65/2 panels of 128
#define NBLK 512

__device__ __forceinline__ unsigned short f2bf(float f) {
  unsigned int u = __float_as_uint(f);
  u = (u + 0x7FFFu + ((u >> 16) & 1u)) >> 16;   // RNE, inputs finite
  return (unsigned short)u;
}

__device__ __forceinline__ void unrank_tile(int t, int& p_out, int& q_out) {
  // triangular pair (p <= q), rank(p,q) = p*(129-p)/2 + (q-p)
  int p = (int)((129.0f - sqrtf((float)(16641 - 8 * t))) * 0.5f);
  p = max(0, min(63, p));
  while ((((p + 1) * (129 - (p + 1))) >> 1) <= t) ++p;
  while (((p * (129 - p)) >> 1) > t) --p;
  p_out = p;
  q_out = p + (t - ((p * (129 - p)) >> 1));
}

// ---------------- 1. normalize + sqrt(2*log2e) scale + bf16; zero d1 counter ----------------
__global__ __launch_bounds__(256) void norm_kernel(const float* __restrict__ zx,
                                                   const float* __restrict__ zy,
                                                   unsigned short* __restrict__ zn,
                                                   unsigned int* __restrict__ counter) {
  if (blockIdx.x == 0 && threadIdx.x == 0) *counter = 0u;
  const int row = blockIdx.x * 4 + (threadIdx.x >> 6);   // 8192 rows, 1 per wave
  const int lane = threadIdx.x & 63;
  const float* src = (row < 4096) ? (zx + (size_t)row * DDIM)
                                  : (zy + (size_t)(row - 4096) * DDIM);
  float4 v = reinterpret_cast<const float4*>(src)[lane];
  float ss = v.x * v.x + v.y * v.y + v.z * v.z + v.w * v.w;
#pragma unroll
  for (int m = 1; m < 64; m <<= 1) ss += __shfl_xor(ss, m);
  const float sc = 1.69864360f * rsqrtf(ss);   // sqrt(2*log2e)/||z||
  ushort4 o;
  o.x = f2bf(v.x * sc); o.y = f2bf(v.y * sc);
  o.z = f2bf(v.z * sc); o.w = f2bf(v.w * sc);
  reinterpret_cast<ushort4*>(zn + (size_t)row * DDIM)[lane] = o;
}

// ---------------- 2. upper-triangle sim GEMM + exp2 row/col sums ----------------
__global__ __launch_bounds__(256, 2) void simtri_kernel(const unsigned short* __restrict__ zn,
                                                        float* __restrict__ partial,
                                                        float* __restrict__ pos) {
  __shared__ unsigned short smem[2][2][128 * 64];
  // XCD-contiguous chunk id: blocks on the same XCD (bid%8) get consecutive
  // chunks -> consecutive row-major tile runs share A/B panels in that L2.
  const int c = (blockIdx.x & 7) * 64 + (blockIdx.x >> 3);
  int start, nt;
  if (c < 32) { start = c * 5;              nt = 5; }   // 2080 = 32*5 + 480*4
  else        { start = 160 + (c - 32) * 4; nt = 4; }

  const int tid = threadIdx.x;
  const int lane = tid & 63;
  const int wid = tid >> 6;
  const int wr = wid >> 1;              // wave row (0/1)
  const int wc = wid & 1;               // wave col (0/1)
  const int hi = lane >> 4, lo = lane & 15;
  const int sw = lo & 7;                // frag-read XOR (== row&7 of this lane's rows)

  const f32x4 z4 = {0.f, 0.f, 0.f, 0.f};
  f32x4 acc[4][4];
#pragma unroll
  for (int m = 0; m < 4; ++m)
#pragma unroll
    for (int n = 0; n < 4; ++n) acc[m][n] = z4;

  // Stage 128x64 bf16 tile: LDS dest LINEAR (16B units), global source
  // pre-swizzled so that LDS[r][ul] holds global unit (ul ^ (r&7)).
  auto stage_one = [&](int buf, int which, int row0, int k0) {
    unsigned short* lb = &smem[buf][which][0];
#pragma unroll
    for (int j = 0; j < 4; ++j) {
      const int u = j * 256 + tid;                 // 16B-unit index, 0..1023
      const int r = u >> 3, ul = u & 7;
      const unsigned short* g =
          zn + (size_t)(row0 + r) * DDIM + k0 + ((ul ^ (r & 7)) << 3);
      unsigned short* l = lb + (size_t)(j * 256 + wid * 64) * 8;  // wave-uniform; HW adds lane*16B
      __builtin_amdgcn_global_load_lds(
          (const __attribute__((address_space(1))) void*)g,
          (__attribute__((address_space(3))) void*)l, 16, 0, 0);
    }
  };
  auto stageT = [&](int buf, int p, int q, int k0) {
    stage_one(buf, 0, p << 7, k0);
    if (p != q) stage_one(buf, 1, q << 7, k0);
  };

  int cp, cq;
  unrank_tile(start, cp, cq);
  stageT(0, cp, cq, 0);
  __syncthreads();

  int buf = 0;
  for (int i = 0; i < nt; ++i) {
    // next tile: row-major successor within the triangle
    int np = cp, nq = cq;
    const bool have_next = (i + 1 < nt);
    if (have_next) { if (cq == 63) { np = cp + 1; nq = np; } else { nq = cq + 1; } }
    const bool isdiag = (cp == cq);
    const bool ispos = (cq == cp + 32);
    const int R0 = cp << 7;
    const int C0 = cq << 7;

#pragma unroll
    for (int kk = 0; kk < 4; ++kk) {
      if (kk < 3) stageT(buf ^ 1, cp, cq, (kk + 1) * 64);
      else if (have_next) stageT(buf ^ 1, np, nq, 0);
      const unsigned short* A = &smem[buf][0][0];
      const unsigned short* Bm = isdiag ? A : &smem[buf][1][0];
#pragma unroll
      for (int ks = 0; ks < 2; ++ks) {
        short8 af[4], bfr[4];
#pragma unroll
        for (int m = 0; m < 4; ++m)
          af[m] = *reinterpret_cast<const short8*>(
              A + ((wr * 64 + m * 16 + lo) * 64 + (((ks * 4 + hi) ^ sw) << 3)));
#pragma unroll
        for (int n = 0; n < 4; ++n)
          bfr[n] = *reinterpret_cast<const short8*>(
              Bm + ((wc * 64 + n * 16 + lo) * 64 + (((ks * 4 + hi) ^ sw) << 3)));
#pragma unroll
        for (int m = 0; m < 4; ++m)
#pragma unroll
          for (int n = 0; n < 4; ++n)
            acc[m][n] = __builtin_amdgcn_mfma_f32_16x16x32_bf16(af[m], bfr[n], acc[m][n], 0, 0, 0);
      }
      buf ^= 1;
      if (kk < 3) __syncthreads();
    }

    // ---- epilogue (before tile-boundary barrier: overlaps staged-load latency) ----
    float rsum[4][4];       // [m][r]  row partial over this wave's 64 cols
    float csum[4];          // [n]     col partial over this wave's 64 rows
#pragma unroll
    for (int m = 0; m < 4; ++m)
#pragma unroll
      for (int r = 0; r < 4; ++r) rsum[m][r] = 0.f;
#pragma unroll
    for (int n = 0; n < 4; ++n) csum[n] = 0.f;

#pragma unroll
    for (int m = 0; m < 4; ++m)
#pragma unroll
      for (int n = 0; n < 4; ++n)
#pragma unroll
        for (int r = 0; r < 4; ++r) {
          const float e = __builtin_amdgcn_exp2f(acc[m][n][r]);
          rsum[m][r] += e;
          csum[n] += e;
        }

    // fixups: diag-exclude / pos harvest (tile-local diagonal, wr==wc waves only)
    if ((isdiag || ispos) && (wr == wc)) {
#pragma unroll
      for (int m = 0; m < 4; ++m)
#pragma unroll
        for (int r = 0; r < 4; ++r)
          if (lo == 4 * hi + r) {
            if (isdiag) rsum[m][r] -= __builtin_amdgcn_exp2f(acc[m][m][r]);
            else        pos[R0 + wr * 64 + m * 16 + lo] = acc[m][m][r];  // log2-domain
          }
    }

    // row-sums: reduce across 16 col-lanes -> slot q*2+wc
#pragma unroll
    for (int m = 0; m < 4; ++m)
#pragma unroll
      for (int r = 0; r < 4; ++r) {
        float s = rsum[m][r];
        s += __shfl_xor(s, 1); s += __shfl_xor(s, 2);
        s += __shfl_xor(s, 4); s += __shfl_xor(s, 8);
        if (lo == 0) {
          const int grow = R0 + wr * 64 + m * 16 + (hi << 2) + r;
          partial[(size_t)(cq * 2 + wc) * NROWS + grow] = s;
        }
      }

    // col-sums: reduce across 4 row-groups -> slot p*2+wr (skip diagonal tile)
    if (!isdiag) {
#pragma unroll
      for (int n = 0; n < 4; ++n) {
        float cs = csum[n];
        cs += __shfl_xor(cs, 16); cs += __shfl_xor(cs, 32);
        if (lane < 16)
          partial[(size_t)(cp * 2 + wr) * NROWS + (C0 + wc * 64 + n * 16 + lane)] = cs;
      }
    }

    // reset acc for next tile
#pragma unroll
    for (int m = 0; m < 4; ++m)
#pragma unroll
      for (int n = 0; n < 4; ++n) acc[m][n] = z4;

    __syncthreads();   // next-tile staged data ready; smem[buf^1] safe to overwrite
    cp = np; cq = nq;
  }
}

// ---------------- 3. per-row loss + full reduction (last-block-done finish) ----------------
__global__ __launch_bounds__(256) void d1_kernel(const float* __restrict__ partial,
                                                 const float* __restrict__ pos,
                                                 float* __restrict__ bsum,
                                                 float* __restrict__ out,
                                                 unsigned int* __restrict__ counter) {
  const int row = blockIdx.x * 256 + threadIdx.x;   // 32 blocks x 256
  float s = 0.f;
#pragma unroll 16
  for (int c = 0; c < 128; ++c) s += partial[(size_t)c * NROWS + row];
  const float L = __log2f(s) - pos[row & 4095];     // log2-domain ce
  const float pt = __builtin_amdgcn_exp2f(-L);
  const float ce = 0.69314718056f * L;
  float f = (1.f - pt) * (1.f - pt) * ce;
#pragma unroll
  for (int m = 1; m < 64; m <<= 1) f += __shfl_xor(f, m);
  __shared__ float wsum[4];
  if ((threadIdx.x & 63) == 0) wsum[threadIdx.x >> 6] = f;
  __syncthreads();
  if (threadIdx.x == 0) {
    bsum[blockIdx.x] = wsum[0] + wsum[1] + wsum[2] + wsum[3];
    __threadfence();
    if (atomicAdd(counter, 1u) == 31u) {        // last block: deterministic finish
      __threadfence();
      float v = 0.f;
#pragma unroll
      for (int c = 0; c < 32; ++c) v += ((const volatile float*)bsum)[c];
      out[0] = 0.25f * v / 8192.f;              // ALPHA * mean
    }
  }
}

extern "C" void kernel_launch(void* const* d_in, const int* in_sizes, int n_in,
                              void* d_out, int out_size, void* d_ws, size_t ws_size,
                              hipStream_t stream) {
  const float* zx = (const float*)d_in[0];
  const float* zy = (const float*)d_in[1];
  float* out = (float*)d_out;

  // workspace (~8.02 MiB): zn bf16 | pos | partial | bsum | counter
  unsigned short* zn = (unsigned short*)d_ws;                      // 8192*256*2 = 4 MiB
  float* pos = (float*)((char*)d_ws + (size_t)NROWS * DDIM * 2);   // 16 KiB
  float* partial = pos + 4096;                                     // 128*8192*4 = 4 MiB
  float* bsum = partial + (size_t)128 * NROWS;                     // 128 B
  unsigned int* counter = (unsigned int*)(bsum + 32);              // 4 B

  norm_kernel<<<2048, 256, 0, stream>>>(zx, zy, zn, counter);
  simtri_kernel<<<NBLK, 256, 0, stream>>>(zn, partial, pos);
  d1_kernel<<<32, 256, 0, stream>>>(partial, pos, bsum, out, counter);
}